// Round 7
// baseline (1035.828 us; speedup 1.0000x reference)
//
#include <hip/hip_runtime.h>
#include <hip/hip_bf16.h>

#define NNODES 100000
#define FD 128
#define NEDGES 640000
#define NB 391            // ceil(NNODES/256)
#define CPG 782           // 128-row chunks per graph
#define GX 172            // grid.x for batched gemms
#define OFFS_U32 100032   // padded NNODES+1
#define BNST 128          // bn-stats blocks per graph

typedef __bf16 bf16x8 __attribute__((ext_vector_type(8)));
typedef __bf16 bf16x4 __attribute__((ext_vector_type(4)));
typedef float f32x4 __attribute__((ext_vector_type(4)));
typedef unsigned short u16x8 __attribute__((ext_vector_type(8)));

__device__ __forceinline__ bf16x8 cvt8(float4 a, float4 b) {
  bf16x8 r;
  r[0] = (__bf16)a.x; r[1] = (__bf16)a.y; r[2] = (__bf16)a.z; r[3] = (__bf16)a.w;
  r[4] = (__bf16)b.x; r[5] = (__bf16)b.y; r[6] = (__bf16)b.z; r[7] = (__bf16)b.w;
  return r;
}

// ---- pack all 6 weight matrices f32[128][128] -> bf16 MFMA fragments ----
// frag f = (c*4+kk)*64 + lane; elem j = W[(c*16+(lane&15))][kk*32+(lane>>4)*8+j]
__global__ __launch_bounds__(256) void packw6_k(
    const float* __restrict__ W0, const float* __restrict__ W1,
    const float* __restrict__ W2, const float* __restrict__ W3,
    const float* __restrict__ W4, const float* __restrict__ W5,
    __bf16* __restrict__ out) {
  const int gidx = blockIdx.x * 256 + threadIdx.x;  // 0..12287
  const int wi = gidx >> 11;
  const int f = gidx & 2047;
  const float* W = wi == 0 ? W0 : wi == 1 ? W1 : wi == 2 ? W2
                 : wi == 3 ? W3 : wi == 4 ? W4 : W5;
  const int c = f >> 8, kk = (f >> 6) & 3, lane = f & 63;
  const int lr = lane & 15, lg = lane >> 4;
  const float* p = W + (c * 16 + lr) * FD + kk * 32 + lg * 8;
  *(bf16x8*)(out + (long)gidx * 8) = cvt8(*(const float4*)p, *(const float4*)(p + 4));
}

// A-row fragment loader: 4 x bf16x8 covering cols {kbase + kk*32 .. +8}.
// AM: 0 = f32, 1 = bf16, 3 = bf16 + fused BN+relu (scsh[0:128]=sc,[128:256]=sh)
template <int AM>
__device__ __forceinline__ void load_arow(const void* __restrict__ A, long row,
                                          int kbase, const float* __restrict__ scsh,
                                          bf16x8 (&af)[4]) {
  if constexpr (AM == 1) {
#pragma unroll
    for (int kk = 0; kk < 4; ++kk)
      af[kk] = *(const bf16x8*)((const __bf16*)A + row * FD + kbase + kk * 32);
  } else if constexpr (AM == 3) {
#pragma unroll
    for (int kk = 0; kk < 4; ++kk) {
      const int k = kbase + kk * 32;
      const bf16x8 r = *(const bf16x8*)((const __bf16*)A + row * FD + k);
      const float4 scx = *(const float4*)(scsh + k);
      const float4 scy = *(const float4*)(scsh + k + 4);
      const float4 shx = *(const float4*)(scsh + 128 + k);
      const float4 shy = *(const float4*)(scsh + 128 + k + 4);
      bf16x8 o;
      o[0] = (__bf16)fmaxf((float)r[0] * scx.x + shx.x, 0.f);
      o[1] = (__bf16)fmaxf((float)r[1] * scx.y + shx.y, 0.f);
      o[2] = (__bf16)fmaxf((float)r[2] * scx.z + shx.z, 0.f);
      o[3] = (__bf16)fmaxf((float)r[3] * scx.w + shx.w, 0.f);
      o[4] = (__bf16)fmaxf((float)r[4] * scy.x + shy.x, 0.f);
      o[5] = (__bf16)fmaxf((float)r[5] * scy.y + shy.y, 0.f);
      o[6] = (__bf16)fmaxf((float)r[6] * scy.z + shy.z, 0.f);
      o[7] = (__bf16)fmaxf((float)r[7] * scy.w + shy.w, 0.f);
      af[kk] = o;
    }
  } else {  // f32
#pragma unroll
    for (int kk = 0; kk < 4; ++kk) {
      const int k = kbase + kk * 32;
      const float* ap = (const float*)A + row * FD + k;
      af[kk] = cvt8(*(const float4*)ap, *(const float4*)(ap + 4));
    }
  }
}

template <int AM>
__device__ __forceinline__ void load_chunk(const void* __restrict__ A, int ch,
                                           int wid, int lr, int kbase,
                                           const float* __restrict__ scsh,
                                           bf16x8 (&af)[2][4], int M) {
  const int rbase = ch * 128 + wid * 32;
#pragma unroll
  for (int t = 0; t < 2; ++t) {
    long row = rbase + t * 16 + lr;
    if (row > M - 1) row = M - 1;  // clamp; stores guarded in epilogue
    load_arow<AM>(A, row, kbase, scsh, af[t]);
  }
}

__device__ __forceinline__ void mma_pass_lds(const __bf16* __restrict__ wl, int lane,
                                             const bf16x8 (&af)[2][4],
                                             f32x4 (&acc)[2][8]) {
#pragma unroll
  for (int c = 0; c < 8; ++c) {
    bf16x8 bw[4];
#pragma unroll
    for (int kk = 0; kk < 4; ++kk)
      bw[kk] = *(const bf16x8*)(wl + ((long)((c * 4 + kk) * 64 + lane)) * 8);
#pragma unroll
    for (int t = 0; t < 2; ++t)
#pragma unroll
      for (int kk = 0; kk < 4; ++kk)
        acc[t][c] = __builtin_amdgcn_mfma_f32_16x16x32_bf16(bw[kk], af[t][kk], acc[t][c], 0, 0, 0);
  }
}

// epilogue: lane holds D[row = rbase+t*16+lr][cols c*16+lg*4 .. +3]
template <bool RELU, bool OUTBF16, bool NT>
__device__ __forceinline__ void epilogue(f32x4 (&acc)[2][8], int ch, int wid,
                                         int lr, int lg,
                                         const float* __restrict__ bias,
                                         void* __restrict__ outg, int M) {
  const int rbase = ch * 128 + wid * 32;
#pragma unroll
  for (int t = 0; t < 2; ++t) {
    const int row = rbase + t * 16 + lr;
    if (row < M) {
#pragma unroll
      for (int c = 0; c < 8; ++c) {
        const int cb = c * 16 + lg * 4;
        f32x4 v = acc[t][c];
        const float4 bv = *(const float4*)(bias + cb);
        v[0] += bv.x; v[1] += bv.y; v[2] += bv.z; v[3] += bv.w;
        if constexpr (RELU) {
#pragma unroll
          for (int j = 0; j < 4; ++j) v[j] = fmaxf(v[j], 0.f);
        }
        if constexpr (OUTBF16) {
          bf16x4 o;
          o[0] = (__bf16)v[0]; o[1] = (__bf16)v[1];
          o[2] = (__bf16)v[2]; o[3] = (__bf16)v[3];
          *(bf16x4*)((__bf16*)outg + (long)row * FD + cb) = o;
        } else {
          f32x4* p = (f32x4*)((float*)outg + (long)row * FD + cb);
          if constexpr (NT) __builtin_nontemporal_store(v, p);
          else *p = v;
        }
      }
    }
  }
}

__device__ __forceinline__ void write_bcopy(const bf16x8 (&af)[2][4], int ch,
                                            int wid, int lr, int kbase,
                                            __bf16* __restrict__ bcopy, int M) {
  const int rbase = ch * 128 + wid * 32;
#pragma unroll
  for (int t = 0; t < 2; ++t) {
    const int row = rbase + t * 16 + lr;
    if (row < M) {
#pragma unroll
      for (int kk = 0; kk < 4; ++kk)
        *(bf16x8*)(bcopy + (long)row * FD + kbase + kk * 32) = af[t][kk];
    }
  }
}

// out[g][M x 128] = f(A0[g]) @ W0^T (+ f(A1[g]) @ W1^T) + bias, opt relu.
// W in LDS (staged once/block); grid-stride chunks of 128 rows with unroll-2
// register double-buffered A-prefetch (next chunk's loads in flight under the
// current chunk's ds_read+MFMA compute). Swapped-operand MFMA epilogue.
template <int A0M, int A1M, bool TWOA, bool RELU, bool OUTBF16, bool WRITEB, bool NT>
__global__ __launch_bounds__(256, 2) void gemm_k(
    const void* __restrict__ A0, long a0s, const void* __restrict__ A1, long a1s,
    const __bf16* __restrict__ W0p, const __bf16* __restrict__ W1p,
    const float* __restrict__ bias, const float* __restrict__ scsh0,
    void* __restrict__ outp, long os, __bf16* __restrict__ bcopy, int M) {
  __shared__ __align__(16) __bf16 wlds[(TWOA ? 2 : 1) * 16384];
  const int g = blockIdx.y;
  const int wid = threadIdx.x >> 6;
  const int lane = threadIdx.x & 63;
  const int lr = lane & 15;
  const int lg = lane >> 4;
  const int kbase = lg * 8;
  const int S = gridDim.x;

  const void* A0g = (const char*)A0 + (long)g * a0s;
  const void* A1g = TWOA ? ((const char*)A1 + (long)g * a1s) : nullptr;
  void* outg = (char*)outp + (long)g * os;
  const float* scshg = (A0M == 3 || A1M == 3) ? (scsh0 + (long)g * 256) : nullptr;

  bf16x8 a0A[2][4], a0B[2][4];
  bf16x8 a1A[2][4], a1B[2][4];  // DCE'd when !TWOA

  const int ch0 = blockIdx.x;
  load_chunk<A0M>(A0g, ch0, wid, lr, kbase, scshg, a0A, M);
  if constexpr (TWOA) load_chunk<A1M>(A1g, ch0, wid, lr, kbase, scshg, a1A, M);

  // stage packed W into LDS (linear copy, 16B per thread per iter)
  for (int it = threadIdx.x; it < 2048; it += 256)
    *(bf16x8*)(wlds + (long)it * 8) = *(const bf16x8*)(W0p + (long)it * 8);
  if constexpr (TWOA) {
    for (int it = threadIdx.x; it < 2048; it += 256)
      *(bf16x8*)(wlds + 16384 + (long)it * 8) = *(const bf16x8*)(W1p + (long)it * 8);
  }
  __syncthreads();

  f32x4 acc[2][8];
  for (int ch = ch0; ch < CPG; ch += 2 * S) {
    const int chB = ch + S;
    // ---- body A: compute chunk ch, prefetch chunk chB
    load_chunk<A0M>(A0g, chB, wid, lr, kbase, scshg, a0B, M);
    if constexpr (TWOA) load_chunk<A1M>(A1g, chB, wid, lr, kbase, scshg, a1B, M);
#pragma unroll
    for (int t = 0; t < 2; ++t)
#pragma unroll
      for (int c = 0; c < 8; ++c) acc[t][c] = (f32x4){0.f, 0.f, 0.f, 0.f};
    mma_pass_lds(wlds, lane, a0A, acc);
    if constexpr (TWOA) mma_pass_lds(wlds + 16384, lane, a1A, acc);
    if constexpr (WRITEB) write_bcopy(a0A, ch, wid, lr, kbase, bcopy, M);
    epilogue<RELU, OUTBF16, NT>(acc, ch, wid, lr, lg, bias, outg, M);
    // ---- body B: compute chunk chB, prefetch chunk ch+2S
    load_chunk<A0M>(A0g, ch + 2 * S, wid, lr, kbase, scshg, a0A, M);
    if constexpr (TWOA) load_chunk<A1M>(A1g, ch + 2 * S, wid, lr, kbase, scshg, a1A, M);
#pragma unroll
    for (int t = 0; t < 2; ++t)
#pragma unroll
      for (int c = 0; c < 8; ++c) acc[t][c] = (f32x4){0.f, 0.f, 0.f, 0.f};
    mma_pass_lds(wlds, lane, a0B, acc);
    if constexpr (TWOA) mma_pass_lds(wlds + 16384, lane, a1B, acc);
    if constexpr (WRITEB) write_bcopy(a0B, chB, wid, lr, kbase, bcopy, M);
    epilogue<RELU, OUTBF16, NT>(acc, chB, wid, lr, lg, bias, outg, M);
  }
}

// ---- BN stats from bf16 h1 (vectorized, 2-stage) ----
__global__ __launch_bounds__(256) void bn_stats1_k(const __bf16* __restrict__ h3,
                                                   float* __restrict__ pblk2) {
  const int g = blockIdx.y;
  const __bf16* h = h3 + (long)g * NNODES * FD;
  const int tid = threadIdx.x;
  const int cb = (tid & 15) * 8;
  const int rg = tid >> 4;  // 0..15
  float s[8], ss[8];
#pragma unroll
  for (int j = 0; j < 8; ++j) { s[j] = 0.f; ss[j] = 0.f; }
  for (int r = blockIdx.x * 16 + rg; r < NNODES; r += BNST * 16) {
    const bf16x8 v = *(const bf16x8*)(h + (long)r * FD + cb);
#pragma unroll
    for (int j = 0; j < 8; ++j) {
      const float x = (float)v[j];
      s[j] += x;
      ss[j] += x * x;
    }
  }
  __shared__ float ls[16][256];
#pragma unroll
  for (int j = 0; j < 8; ++j) {
    ls[rg][cb + j] = s[j];
    ls[rg][128 + cb + j] = ss[j];
  }
  __syncthreads();
  float a = 0.f;
#pragma unroll
  for (int q = 0; q < 16; ++q) a += ls[q][tid];
  pblk2[((long)g * BNST + blockIdx.x) * 256 + tid] = a;
}

__global__ __launch_bounds__(256) void bn_final2_k(const float* __restrict__ pblk2,
                                                   const float* __restrict__ gamma,
                                                   const float* __restrict__ beta,
                                                   float* __restrict__ scsh3) {
  __shared__ float s_ss[128];
  const int g = blockIdx.y;
  const int tid = threadIdx.x;
  const float* p = pblk2 + (long)g * BNST * 256;
  float s = 0.f;
  for (int r = 0; r < BNST; ++r) s += p[r * 256 + tid];
  if (tid >= 128) s_ss[tid - 128] = s;
  __syncthreads();
  if (tid < 128) {
    const float mu = s / (float)NNODES;
    const float var = s_ss[tid] / (float)NNODES - mu * mu;
    const float sc = rsqrtf(var + 1e-5f) * gamma[tid];
    scsh3[g * 256 + tid] = sc;
    scsh3[g * 256 + 128 + tid] = beta[tid] - mu * sc;
  }
}

// ---- batched (3-graph) counting-sort, rank-trick (atomics only in hist) ----

__global__ __launch_bounds__(256) void hist_rank3_k(const int* __restrict__ edges,
                                                    unsigned* __restrict__ deg3,
                                                    unsigned short* __restrict__ rank3) {
  const int g = blockIdx.y;
  const int e = blockIdx.x * 256 + threadIdx.x;
  if (e < NEDGES) {
    const int d = edges[(long)g * 2 * NEDGES + NEDGES + e];
    const unsigned r = atomicAdd(&deg3[(long)g * NNODES + d], 1u);
    rank3[(long)g * NEDGES + e] = (unsigned short)r;
  }
}

__global__ __launch_bounds__(256) void blocksum3_k(const unsigned* __restrict__ deg3,
                                                   unsigned* __restrict__ bsum3) {
  __shared__ unsigned s[256];
  const int g = blockIdx.y;
  const int i = blockIdx.x * 256 + threadIdx.x;
  s[threadIdx.x] = (i < NNODES) ? deg3[(long)g * NNODES + i] : 0u;
  __syncthreads();
#pragma unroll
  for (int o = 128; o > 0; o >>= 1) {
    if (threadIdx.x < o) s[threadIdx.x] += s[threadIdx.x + o];
    __syncthreads();
  }
  if (threadIdx.x == 0) bsum3[g * NB + blockIdx.x] = s[0];
}

__global__ __launch_bounds__(512) void scanb3_k(const unsigned* __restrict__ bsum3,
                                                unsigned* __restrict__ boffs3,
                                                unsigned* __restrict__ offs3) {
  __shared__ unsigned s[512];
  const int g = blockIdx.y;
  const unsigned v = (threadIdx.x < NB) ? bsum3[g * NB + threadIdx.x] : 0u;
  s[threadIdx.x] = v;
  __syncthreads();
#pragma unroll
  for (int o = 1; o < 512; o <<= 1) {
    unsigned t = (threadIdx.x >= o) ? s[threadIdx.x - o] : 0u;
    __syncthreads();
    s[threadIdx.x] += t;
    __syncthreads();
  }
  if (threadIdx.x < NB) boffs3[g * NB + threadIdx.x] = s[threadIdx.x] - v;
  if (threadIdx.x == 0) offs3[(long)g * OFFS_U32 + NNODES] = NEDGES;
}

__global__ __launch_bounds__(256) void offsets3_k(const unsigned* __restrict__ deg3,
                                                  const unsigned* __restrict__ boffs3,
                                                  unsigned* __restrict__ offs3) {
  __shared__ unsigned s[256];
  const int g = blockIdx.y;
  const int i = blockIdx.x * 256 + threadIdx.x;
  const unsigned v = (i < NNODES) ? deg3[(long)g * NNODES + i] : 0u;
  s[threadIdx.x] = v;
  __syncthreads();
#pragma unroll
  for (int o = 1; o < 256; o <<= 1) {
    unsigned t = (threadIdx.x >= o) ? s[threadIdx.x - o] : 0u;
    __syncthreads();
    s[threadIdx.x] += t;
    __syncthreads();
  }
  const unsigned excl = s[threadIdx.x] - v + boffs3[g * NB + blockIdx.x];
  if (i < NNODES) offs3[(long)g * OFFS_U32 + i] = excl;
}

__global__ __launch_bounds__(256) void scat3_k(const int* __restrict__ edges,
                                               const unsigned* __restrict__ offs3,
                                               const unsigned short* __restrict__ rank3,
                                               int* __restrict__ ssrc3) {
  const int g = blockIdx.y;
  const int e = blockIdx.x * 256 + threadIdx.x;
  if (e < NEDGES) {
    const int s = edges[(long)g * 2 * NEDGES + e];
    const int d = edges[(long)g * 2 * NEDGES + NEDGES + e];
    const unsigned p = offs3[(long)g * OFFS_U32 + d] + rank3[(long)g * NEDGES + e];
    ssrc3[(long)g * NEDGES + p] = s;
  }
}

// 16 lanes per node; max over in-edges (bf16 >= 0 -> u16 bit-compare exact).
__global__ __launch_bounds__(256) void agg_k(const unsigned short* __restrict__ m,
                                             long ms, const int* __restrict__ ssrc3,
                                             const unsigned* __restrict__ offs3,
                                             unsigned short* __restrict__ agg3) {
  const int g = blockIdx.y;
  const unsigned short* mg = m + (long)g * ms;
  const int* ssrc = ssrc3 + (long)g * NEDGES;
  const unsigned* offs = offs3 + (long)g * OFFS_U32;
  unsigned short* agg = agg3 + (long)g * NNODES * FD;

  const int gid = blockIdx.x * 256 + threadIdx.x;
  const int node = gid >> 4;
  if (node >= NNODES) return;
  const int fl = (gid & 15) * 8;
  const unsigned beg = offs[node], end = offs[node + 1];
  u16x8 acc = {0, 0, 0, 0, 0, 0, 0, 0};
  unsigned i = beg;
  for (; i + 2 <= end; i += 2) {
    const int s0 = ssrc[i];
    const int s1 = ssrc[i + 1];
    const u16x8 v0 = *(const u16x8*)(mg + (long)s0 * FD + fl);
    const u16x8 v1 = *(const u16x8*)(mg + (long)s1 * FD + fl);
#pragma unroll
    for (int j = 0; j < 8; ++j) {
      const unsigned short mx = v0[j] > v1[j] ? v0[j] : v1[j];
      acc[j] = mx > acc[j] ? mx : acc[j];
    }
  }
  if (i < end) {
    const u16x8 v = *(const u16x8*)(mg + (long)ssrc[i] * FD + fl);
#pragma unroll
    for (int j = 0; j < 8; ++j) acc[j] = v[j] > acc[j] ? v[j] : acc[j];
  }
  *(u16x8*)(agg + (long)node * FD + fl) = acc;
}

__global__ __launch_bounds__(256) void zero_k(float4* __restrict__ p, long n4) {
  const long i = (long)blockIdx.x * 256 + threadIdx.x;
  if (i < n4) p[i] = (float4){0.f, 0.f, 0.f, 0.f};
}

extern "C" void kernel_launch(void* const* d_in, const int* in_sizes, int n_in,
                              void* d_out, int out_size, void* d_ws, size_t ws_size,
                              hipStream_t stream) {
  const float* feat = (const float*)d_in[0];
  const int* edges = (const int*)d_in[1];
  const float* Wp1 = (const float*)d_in[2];
  const float* bp1 = (const float*)d_in[3];
  const float* Ws1 = (const float*)d_in[4];
  const float* Wn1 = (const float*)d_in[5];
  const float* b1 = (const float*)d_in[6];
  const float* gamma = (const float*)d_in[7];
  const float* beta = (const float*)d_in[8];
  const float* Wp2 = (const float*)d_in[9];
  const float* bp2 = (const float*)d_in[10];
  const float* Ws2 = (const float*)d_in[11];
  const float* Wn2 = (const float*)d_in[12];
  const float* b2 = (const float*)d_in[13];

  const long SZ_BF = 25600000;   // bf16 [N][128] bytes
  const long SZ_F32 = 51200000;  // f32  [N][128] bytes

  // workspace layout (bytes, 128B-aligned)
  char* w = (char*)d_ws;
  __bf16* m1 = (__bf16*)w;                          // 25.6 MB
  __bf16* featb = (__bf16*)(w + 25600000);          // 25.6 MB
  __bf16* h1b3 = (__bf16*)(w + 51200000);           // 76.8 MB (3x pre-BN h1)
  __bf16* aggb3 = (__bf16*)(w + 128000000);         // 76.8 MB
  __bf16* m2_3 = (__bf16*)(w + 204800000);          // 76.8 MB
  __bf16* wpk = (__bf16*)(w + 281600000);           // 192 KB packed weights
  unsigned* deg3 = (unsigned*)(w + 281796608);      // 1.2 MB
  unsigned* offs3 = (unsigned*)(w + 282996608);     // 1.2 MB
  unsigned* bsum3 = (unsigned*)(w + 284196992);     // 4.7 KB
  unsigned* boffs3 = (unsigned*)(w + 284201728);    // 4.7 KB
  unsigned short* rank3 = (unsigned short*)(w + 284206464);  // 3.84 MB
  int* ssrc3 = (int*)(w + 288046464);               // 7.68 MB
  float* pblk2 = (float*)(w + 295726464);           // 393 KB (3 x 128 x 256)
  float* scsh3 = (float*)(w + 296126464);           // 3 KB

  __bf16* Wp1p = wpk;
  __bf16* Ws1p = wpk + 16384;
  __bf16* Wn1p = wpk + 2 * 16384;
  __bf16* Wp2p = wpk + 3 * 16384;
  __bf16* Ws2p = wpk + 4 * 16384;
  __bf16* Wn2p = wpk + 5 * 16384;

  const dim3 blk(256);
  const int edgeGrid = (NEDGES + 255) / 256;             // 2500
  const int aggGrid = (NNODES * 16 + 255) / 256;         // 6250
  const int degZeroGrid = (3 * NNODES / 4 + 255) / 256;  // 293

  // pack all weights in one dispatch
  packw6_k<<<48, blk, 0, stream>>>(Wp1, Ws1, Wn1, Wp2, Ws2, Wn2, wpk);

  // batched edge bucketing (counting sort by dst) for all 3 graphs
  zero_k<<<degZeroGrid, blk, 0, stream>>>((float4*)deg3, 3L * NNODES / 4);
  hist_rank3_k<<<dim3(edgeGrid, 3), blk, 0, stream>>>(edges, deg3, rank3);
  blocksum3_k<<<dim3(NB, 3), blk, 0, stream>>>(deg3, bsum3);
  scanb3_k<<<dim3(1, 3), dim3(512), 0, stream>>>(bsum3, boffs3, offs3);
  offsets3_k<<<dim3(NB, 3), blk, 0, stream>>>(deg3, boffs3, offs3);
  scat3_k<<<dim3(edgeGrid, 3), blk, 0, stream>>>(edges, offs3, rank3, ssrc3);

  // head: m1 = relu(feat@Wp1^T + bp1) (bf16), plus featb = bf16(feat)
  gemm_k<0, 0, false, true, true, true, false><<<dim3(391, 1), blk, 0, stream>>>(
      feat, 0, nullptr, 0, Wp1p, nullptr, bp1, nullptr, m1, 0, featb, NNODES);

  // layer 1 (batched): agg1[g] = segmax_g(m1);
  // h1[g] = agg1[g]@Wn1^T + featb@Ws1^T + b1 (bf16)
  agg_k<<<dim3(aggGrid, 3), blk, 0, stream>>>((const unsigned short*)m1, 0L,
                                              ssrc3, offs3, (unsigned short*)aggb3);
  gemm_k<1, 1, true, false, true, false, false><<<dim3(GX, 3), blk, 0, stream>>>(
      aggb3, SZ_BF, featb, 0, Wn1p, Ws1p, b1, nullptr, h1b3, SZ_BF, nullptr, NNODES);

  // BN stats from bf16 h1
  bn_stats1_k<<<dim3(BNST, 3), blk, 0, stream>>>(h1b3, pblk2);
  bn_final2_k<<<dim3(1, 3), blk, 0, stream>>>(pblk2, gamma, beta, scsh3);

  // layer 2 (batched): m2[g] = relu(bnrelu(h1[g])@Wp2^T + bp2)
  gemm_k<3, 0, false, true, true, false, false><<<dim3(GX, 3), blk, 0, stream>>>(
      h1b3, SZ_BF, nullptr, 0, Wp2p, nullptr, bp2, scsh3, m2_3, SZ_BF, nullptr, NNODES);
  agg_k<<<dim3(aggGrid, 3), blk, 0, stream>>>((const unsigned short*)m2_3,
                                              (long)NNODES * FD, ssrc3, offs3,
                                              (unsigned short*)aggb3);
  // out[g] = bnrelu(h1[g])@Ws2^T + agg2[g]@Wn2^T + b2 -> d_out (f32, nontemporal)
  gemm_k<3, 1, true, false, false, false, true><<<dim3(GX, 3), blk, 0, stream>>>(
      h1b3, SZ_BF, aggb3, SZ_BF, Ws2p, Wn2p, b2, scsh3, d_out, SZ_F32, nullptr, NNODES);
}

// Round 8
// 569.167 us; speedup vs baseline: 1.8199x; 1.8199x over previous
//
#include <hip/hip_runtime.h>
#include <hip/hip_bf16.h>

#define NNODES 100000
#define FD 128
#define NEDGES 640000
#define NB 391            // ceil(NNODES/256)
#define GRID1 1564        // ceil(NNODES/64) : 64-row gemm blocks
#define OFFS_U32 100032   // padded NNODES+1
#define BNRED 64

typedef __bf16 bf16x8 __attribute__((ext_vector_type(8)));
typedef __bf16 bf16x4 __attribute__((ext_vector_type(4)));
typedef float f32x4 __attribute__((ext_vector_type(4)));
typedef unsigned short u16x8 __attribute__((ext_vector_type(8)));

__device__ __forceinline__ bf16x8 cvt8(float4 a, float4 b) {
  bf16x8 r;
  r[0] = (__bf16)a.x; r[1] = (__bf16)a.y; r[2] = (__bf16)a.z; r[3] = (__bf16)a.w;
  r[4] = (__bf16)b.x; r[5] = (__bf16)b.y; r[6] = (__bf16)b.z; r[7] = (__bf16)b.w;
  return r;
}

// ---- pack all 6 weight matrices f32[128][128] -> bf16 MFMA fragments ----
// frag f = (c*4+kk)*64 + lane; elem j = W[(c*16+(lane&15))][kk*32+(lane>>4)*8+j]
__global__ __launch_bounds__(256) void packw6_k(
    const float* __restrict__ W0, const float* __restrict__ W1,
    const float* __restrict__ W2, const float* __restrict__ W3,
    const float* __restrict__ W4, const float* __restrict__ W5,
    __bf16* __restrict__ out) {
  const int gidx = blockIdx.x * 256 + threadIdx.x;  // 0..12287
  const int wi = gidx >> 11;
  const int f = gidx & 2047;
  const float* W = wi == 0 ? W0 : wi == 1 ? W1 : wi == 2 ? W2
                 : wi == 3 ? W3 : wi == 4 ? W4 : W5;
  const int c = f >> 8, kk = (f >> 6) & 3, lane = f & 63;
  const int lr = lane & 15, lg = lane >> 4;
  const float* p = W + (c * 16 + lr) * FD + kk * 32 + lg * 8;
  *(bf16x8*)(out + (long)gidx * 8) = cvt8(*(const float4*)p, *(const float4*)(p + 4));
}

// A-row fragment loader: 4 x bf16x8 covering cols {kbase + kk*32 .. +8}.
// AM: 0 = f32, 1 = bf16, 3 = bf16 + fused BN+relu (scsh[0:128]=sc,[128:256]=sh)
template <int AM>
__device__ __forceinline__ void load_arow(const void* __restrict__ A, long row,
                                          int kbase, const float* __restrict__ scsh,
                                          bf16x8 (&af)[4]) {
  if constexpr (AM == 1) {
#pragma unroll
    for (int kk = 0; kk < 4; ++kk)
      af[kk] = *(const bf16x8*)((const __bf16*)A + row * FD + kbase + kk * 32);
  } else if constexpr (AM == 3) {
#pragma unroll
    for (int kk = 0; kk < 4; ++kk) {
      const int k = kbase + kk * 32;
      const bf16x8 r = *(const bf16x8*)((const __bf16*)A + row * FD + k);
      const float4 scx = *(const float4*)(scsh + k);
      const float4 scy = *(const float4*)(scsh + k + 4);
      const float4 shx = *(const float4*)(scsh + 128 + k);
      const float4 shy = *(const float4*)(scsh + 128 + k + 4);
      bf16x8 o;
      o[0] = (__bf16)fmaxf((float)r[0] * scx.x + shx.x, 0.f);
      o[1] = (__bf16)fmaxf((float)r[1] * scx.y + shx.y, 0.f);
      o[2] = (__bf16)fmaxf((float)r[2] * scx.z + shx.z, 0.f);
      o[3] = (__bf16)fmaxf((float)r[3] * scx.w + shx.w, 0.f);
      o[4] = (__bf16)fmaxf((float)r[4] * scy.x + shy.x, 0.f);
      o[5] = (__bf16)fmaxf((float)r[5] * scy.y + shy.y, 0.f);
      o[6] = (__bf16)fmaxf((float)r[6] * scy.z + shy.z, 0.f);
      o[7] = (__bf16)fmaxf((float)r[7] * scy.w + shy.w, 0.f);
      af[kk] = o;
    }
  } else {  // f32
#pragma unroll
    for (int kk = 0; kk < 4; ++kk) {
      const int k = kbase + kk * 32;
      const float* ap = (const float*)A + row * FD + k;
      af[kk] = cvt8(*(const float4*)ap, *(const float4*)(ap + 4));
    }
  }
}

// out[g][M x 128] = f(A0[g]) @ W0^T (+ f(A1[g]) @ W1^T) + bias, opt relu.
// Column-split waves: block = 64 rows; wave (rw = wid&1, cw = wid>>1) owns
// rows rbase..+32, cols cw*64..+64 -> acc[2][4] (32 VGPR), 16 W-frags/pass.
// Swapped-operand MFMA: lane holds D[row=rbase+t*16+lr][col=cw*64+c*16+lg*4+j]
// -> vectorized 16B (f32) / 8B (bf16) stores.
// WRITEB: cw==0 waves also emit bf16 copy of A0 rows (head -> featb).
// STATS: per-block column sum/sumsq -> pblk (batched per g).
template <int A0M, int A1M, bool TWOA, bool RELU, bool OUTBF16, bool STATS, bool WRITEB>
__global__ __launch_bounds__(256, 4) void gemm_k(
    const void* __restrict__ A0, long a0s, const void* __restrict__ A1, long a1s,
    const __bf16* __restrict__ W0p, const __bf16* __restrict__ W1p,
    const float* __restrict__ bias, const float* __restrict__ scsh0,
    void* __restrict__ outp, long os, float* __restrict__ pblk,
    __bf16* __restrict__ bcopy, int M) {
  const int g = blockIdx.y;
  const int wid = threadIdx.x >> 6;
  const int rw = wid & 1;
  const int cw = wid >> 1;
  const int lane = threadIdx.x & 63;
  const int lr = lane & 15;
  const int lg = lane >> 4;
  const int kbase = lg * 8;
  const int rbase = blockIdx.x * 64 + rw * 32;
  __shared__ float s_red[2][4][64];

  const void* A0g = (const char*)A0 + (long)g * a0s;
  const void* A1g = (const char*)A1 + (TWOA ? (long)g * a1s : 0);
  void* outg = (char*)outp + (long)g * os;
  const float* scshg = (A0M == 3 || A1M == 3) ? scsh0 + (long)g * 256 : nullptr;
  float* pblkg = STATS ? pblk + (long)g * ((long)GRID1 * 256) : nullptr;

  if constexpr (!STATS) {
    if (rbase >= M) return;  // wave-uniform; no barriers in this path
  }

  f32x4 acc[2][4];
#pragma unroll
  for (int t = 0; t < 2; ++t)
#pragma unroll
    for (int c = 0; c < 4; ++c) acc[t][c] = (f32x4){0.f, 0.f, 0.f, 0.f};

  {
    bf16x8 a0[2][4];
#pragma unroll
    for (int t = 0; t < 2; ++t) {
      long row = rbase + t * 16 + lr;
      if (row > M - 1) row = M - 1;  // clamp; stores guarded in epilogue
      load_arow<A0M>(A0g, row, kbase, scshg, a0[t]);
    }
    if constexpr (WRITEB) {
      if (cw == 0) {
#pragma unroll
        for (int t = 0; t < 2; ++t) {
          const int row = rbase + t * 16 + lr;
          if (row < M)
#pragma unroll
            for (int kk = 0; kk < 4; ++kk)
              *(bf16x8*)(bcopy + (long)row * FD + kbase + kk * 32) = a0[t][kk];
        }
      }
    }
#pragma unroll
    for (int c = 0; c < 4; ++c) {
      bf16x8 bw[4];
#pragma unroll
      for (int kk = 0; kk < 4; ++kk)
        bw[kk] = *(const bf16x8*)(W0p + ((long)(((cw * 4 + c) * 4 + kk) * 64 + lane)) * 8);
#pragma unroll
      for (int t = 0; t < 2; ++t)
#pragma unroll
        for (int kk = 0; kk < 4; ++kk)
          acc[t][c] = __builtin_amdgcn_mfma_f32_16x16x32_bf16(bw[kk], a0[t][kk], acc[t][c], 0, 0, 0);
    }
  }
  if constexpr (TWOA) {
    bf16x8 a1[2][4];
#pragma unroll
    for (int t = 0; t < 2; ++t) {
      long row = rbase + t * 16 + lr;
      if (row > M - 1) row = M - 1;
      load_arow<A1M>(A1g, row, kbase, scshg, a1[t]);
    }
#pragma unroll
    for (int c = 0; c < 4; ++c) {
      bf16x8 bw[4];
#pragma unroll
      for (int kk = 0; kk < 4; ++kk)
        bw[kk] = *(const bf16x8*)(W1p + ((long)(((cw * 4 + c) * 4 + kk) * 64 + lane)) * 8);
#pragma unroll
      for (int t = 0; t < 2; ++t)
#pragma unroll
        for (int kk = 0; kk < 4; ++kk)
          acc[t][c] = __builtin_amdgcn_mfma_f32_16x16x32_bf16(bw[kk], a1[t][kk], acc[t][c], 0, 0, 0);
    }
  }

  // epilogue: lane holds D[row = rbase+t*16+lr][cols cw*64 + c*16 + lg*4 .. +3]
  float ps[4][4], pss[4][4];
  if constexpr (STATS) {
#pragma unroll
    for (int c = 0; c < 4; ++c)
#pragma unroll
      for (int j = 0; j < 4; ++j) { ps[c][j] = 0.f; pss[c][j] = 0.f; }
  }

#pragma unroll
  for (int t = 0; t < 2; ++t) {
    const int row = rbase + t * 16 + lr;
    const bool ok = row < M;
#pragma unroll
    for (int c = 0; c < 4; ++c) {
      const int cb = cw * 64 + c * 16 + lg * 4;
      f32x4 v = acc[t][c];
      if (bias) {
        const float4 bv = *(const float4*)(bias + cb);
        v[0] += bv.x; v[1] += bv.y; v[2] += bv.z; v[3] += bv.w;
      }
      if constexpr (STATS) {
        if (ok) {
#pragma unroll
          for (int j = 0; j < 4; ++j) { ps[c][j] += v[j]; pss[c][j] += v[j] * v[j]; }
        }
      }
      if constexpr (RELU) {
#pragma unroll
        for (int j = 0; j < 4; ++j) v[j] = fmaxf(v[j], 0.f);
      }
      if (ok) {
        if constexpr (OUTBF16) {
          bf16x4 o;
          o[0] = (__bf16)v[0]; o[1] = (__bf16)v[1];
          o[2] = (__bf16)v[2]; o[3] = (__bf16)v[3];
          *(bf16x4*)((__bf16*)outg + (long)row * FD + cb) = o;
        } else {
          *(f32x4*)((float*)outg + (long)row * FD + cb) = v;
        }
      }
    }
  }

  if constexpr (STATS) {
    // reduce over the 16 lr-lanes (rows) within each lg group
#pragma unroll
    for (int c = 0; c < 4; ++c)
#pragma unroll
      for (int j = 0; j < 4; ++j) {
        float s = ps[c][j], q = pss[c][j];
        s += __shfl_xor(s, 1); s += __shfl_xor(s, 2);
        s += __shfl_xor(s, 4); s += __shfl_xor(s, 8);
        q += __shfl_xor(q, 1); q += __shfl_xor(q, 2);
        q += __shfl_xor(q, 4); q += __shfl_xor(q, 8);
        if (lr == 0) {
          s_red[0][wid][c * 16 + lg * 4 + j] = s;
          s_red[1][wid][c * 16 + lg * 4 + j] = q;
        }
      }
    __syncthreads();
    const int tid = threadIdx.x;
    const int wh = tid >> 7, cg = tid & 127;
    const int cwi = cg >> 6, cl = cg & 63;
    pblkg[(long)blockIdx.x * 256 + tid] =
        s_red[wh][cwi * 2 + 0][cl] + s_red[wh][cwi * 2 + 1][cl];
  }
}

// ---- BN partial reductions -> scale/shift (batched over g) ----
__global__ __launch_bounds__(256) void bn_red1_k(const float* __restrict__ pblk,
                                                 float* __restrict__ pblk2) {
  const int g = blockIdx.y;
  const float* p = pblk + (long)g * GRID1 * 256;
  float s = 0.f;
  for (int r = blockIdx.x; r < GRID1; r += BNRED) s += p[(long)r * 256 + threadIdx.x];
  pblk2[((long)g * BNRED + blockIdx.x) * 256 + threadIdx.x] = s;
}

__global__ __launch_bounds__(256) void bn_final2_k(const float* __restrict__ pblk2,
                                                   const float* __restrict__ gamma,
                                                   const float* __restrict__ beta,
                                                   float* __restrict__ scsh3) {
  __shared__ float s_ss[128];
  const int g = blockIdx.y;
  const int tid = threadIdx.x;
  const float* p = pblk2 + (long)g * BNRED * 256;
  float s = 0.f;
#pragma unroll
  for (int r = 0; r < BNRED; ++r) s += p[r * 256 + tid];
  if (tid >= 128) s_ss[tid - 128] = s;
  __syncthreads();
  if (tid < 128) {
    const float mu = s / (float)NNODES;
    const float var = s_ss[tid] / (float)NNODES - mu * mu;
    const float sc = rsqrtf(var + 1e-5f) * gamma[tid];
    scsh3[g * 256 + tid] = sc;
    scsh3[g * 256 + 128 + tid] = beta[tid] - mu * sc;
  }
}

// ---- batched (3-graph) counting-sort, rank-trick (atomics only in hist) ----

__global__ __launch_bounds__(256) void hist_rank3_k(const int* __restrict__ edges,
                                                    unsigned* __restrict__ deg3,
                                                    unsigned short* __restrict__ rank3) {
  const int g = blockIdx.y;
  const int e = blockIdx.x * 256 + threadIdx.x;
  if (e < NEDGES) {
    const int d = edges[(long)g * 2 * NEDGES + NEDGES + e];
    const unsigned r = atomicAdd(&deg3[(long)g * NNODES + d], 1u);
    rank3[(long)g * NEDGES + e] = (unsigned short)r;
  }
}

__global__ __launch_bounds__(256) void blocksum3_k(const unsigned* __restrict__ deg3,
                                                   unsigned* __restrict__ bsum3) {
  __shared__ unsigned s[256];
  const int g = blockIdx.y;
  const int i = blockIdx.x * 256 + threadIdx.x;
  s[threadIdx.x] = (i < NNODES) ? deg3[(long)g * NNODES + i] : 0u;
  __syncthreads();
#pragma unroll
  for (int o = 128; o > 0; o >>= 1) {
    if (threadIdx.x < o) s[threadIdx.x] += s[threadIdx.x + o];
    __syncthreads();
  }
  if (threadIdx.x == 0) bsum3[g * NB + blockIdx.x] = s[0];
}

__global__ __launch_bounds__(512) void scanb3_k(const unsigned* __restrict__ bsum3,
                                                unsigned* __restrict__ boffs3,
                                                unsigned* __restrict__ offs3) {
  __shared__ unsigned s[512];
  const int g = blockIdx.y;
  const unsigned v = (threadIdx.x < NB) ? bsum3[g * NB + threadIdx.x] : 0u;
  s[threadIdx.x] = v;
  __syncthreads();
#pragma unroll
  for (int o = 1; o < 512; o <<= 1) {
    unsigned t = (threadIdx.x >= o) ? s[threadIdx.x - o] : 0u;
    __syncthreads();
    s[threadIdx.x] += t;
    __syncthreads();
  }
  if (threadIdx.x < NB) boffs3[g * NB + threadIdx.x] = s[threadIdx.x] - v;
  if (threadIdx.x == 0) offs3[(long)g * OFFS_U32 + NNODES] = NEDGES;
}

__global__ __launch_bounds__(256) void offsets3_k(const unsigned* __restrict__ deg3,
                                                  const unsigned* __restrict__ boffs3,
                                                  unsigned* __restrict__ offs3) {
  __shared__ unsigned s[256];
  const int g = blockIdx.y;
  const int i = blockIdx.x * 256 + threadIdx.x;
  const unsigned v = (i < NNODES) ? deg3[(long)g * NNODES + i] : 0u;
  s[threadIdx.x] = v;
  __syncthreads();
#pragma unroll
  for (int o = 1; o < 256; o <<= 1) {
    unsigned t = (threadIdx.x >= o) ? s[threadIdx.x - o] : 0u;
    __syncthreads();
    s[threadIdx.x] += t;
    __syncthreads();
  }
  const unsigned excl = s[threadIdx.x] - v + boffs3[g * NB + blockIdx.x];
  if (i < NNODES) offs3[(long)g * OFFS_U32 + i] = excl;
}

__global__ __launch_bounds__(256) void scat3_k(const int* __restrict__ edges,
                                               const unsigned* __restrict__ offs3,
                                               const unsigned short* __restrict__ rank3,
                                               int* __restrict__ ssrc3) {
  const int g = blockIdx.y;
  const int e = blockIdx.x * 256 + threadIdx.x;
  if (e < NEDGES) {
    const int s = edges[(long)g * 2 * NEDGES + e];
    const int d = edges[(long)g * 2 * NEDGES + NEDGES + e];
    const unsigned p = offs3[(long)g * OFFS_U32 + d] + rank3[(long)g * NEDGES + e];
    ssrc3[(long)g * NEDGES + p] = s;
  }
}

// 16 lanes per node; max over in-edges (bf16 >= 0 -> u16 bit-compare exact).
__global__ __launch_bounds__(256) void agg_k(const unsigned short* __restrict__ m,
                                             long ms, const int* __restrict__ ssrc3,
                                             const unsigned* __restrict__ offs3,
                                             unsigned short* __restrict__ agg3) {
  const int g = blockIdx.y;
  const unsigned short* mg = m + (long)g * ms;
  const int* ssrc = ssrc3 + (long)g * NEDGES;
  const unsigned* offs = offs3 + (long)g * OFFS_U32;
  unsigned short* agg = agg3 + (long)g * NNODES * FD;

  const int gid = blockIdx.x * 256 + threadIdx.x;
  const int node = gid >> 4;
  if (node >= NNODES) return;
  const int fl = (gid & 15) * 8;
  const unsigned beg = offs[node], end = offs[node + 1];
  u16x8 acc = {0, 0, 0, 0, 0, 0, 0, 0};
  unsigned i = beg;
  for (; i + 2 <= end; i += 2) {
    const int s0 = ssrc[i];
    const int s1 = ssrc[i + 1];
    const u16x8 v0 = *(const u16x8*)(mg + (long)s0 * FD + fl);
    const u16x8 v1 = *(const u16x8*)(mg + (long)s1 * FD + fl);
#pragma unroll
    for (int j = 0; j < 8; ++j) {
      const unsigned short mx = v0[j] > v1[j] ? v0[j] : v1[j];
      acc[j] = mx > acc[j] ? mx : acc[j];
    }
  }
  if (i < end) {
    const u16x8 v = *(const u16x8*)(mg + (long)ssrc[i] * FD + fl);
#pragma unroll
    for (int j = 0; j < 8; ++j) acc[j] = v[j] > acc[j] ? v[j] : acc[j];
  }
  *(u16x8*)(agg + (long)node * FD + fl) = acc;
}

__global__ __launch_bounds__(256) void zero_k(float4* __restrict__ p, long n4) {
  const long i = (long)blockIdx.x * 256 + threadIdx.x;
  if (i < n4) p[i] = (float4){0.f, 0.f, 0.f, 0.f};
}

extern "C" void kernel_launch(void* const* d_in, const int* in_sizes, int n_in,
                              void* d_out, int out_size, void* d_ws, size_t ws_size,
                              hipStream_t stream) {
  const float* feat = (const float*)d_in[0];
  const int* edges = (const int*)d_in[1];
  const float* Wp1 = (const float*)d_in[2];
  const float* bp1 = (const float*)d_in[3];
  const float* Ws1 = (const float*)d_in[4];
  const float* Wn1 = (const float*)d_in[5];
  const float* b1 = (const float*)d_in[6];
  const float* gamma = (const float*)d_in[7];
  const float* beta = (const float*)d_in[8];
  const float* Wp2 = (const float*)d_in[9];
  const float* bp2 = (const float*)d_in[10];
  const float* Ws2 = (const float*)d_in[11];
  const float* Wn2 = (const float*)d_in[12];
  const float* b2 = (const float*)d_in[13];

  const long SZ_BF = 25600000;   // bf16 [N][128] bytes
  const long SZ_F32 = 51200000;  // f32  [N][128] bytes

  // workspace layout (bytes, 128B-aligned)
  char* w = (char*)d_ws;
  __bf16* m1 = (__bf16*)w;                          // 25.6 MB
  __bf16* featb = (__bf16*)(w + 25600000);          // 25.6 MB
  __bf16* h1b3 = (__bf16*)(w + 51200000);           // 76.8 MB (3x pre-BN h1)
  __bf16* aggb3 = (__bf16*)(w + 128000000);         // 76.8 MB
  __bf16* m2_3 = (__bf16*)(w + 204800000);          // 76.8 MB
  // pblk3/pblk2_3 alias the m2_3 region: they are dead before m2 is written
  float* pblk3 = (float*)(w + 204800000);           // 4.80 MB (3 x 1564 x 256)
  float* pblk2_3 = (float*)(w + 209604608);         // 196 KB
  __bf16* wpk = (__bf16*)(w + 281600000);           // 192 KB packed weights
  float* scsh3 = (float*)(w + 281796608);           // 3 KB
  unsigned* deg3 = (unsigned*)(w + 281799680);      // 1.2 MB
  unsigned* offs3 = (unsigned*)(w + 282999680);     // 1.2 MB
  unsigned* bsum3 = (unsigned*)(w + 284200064);     // 4.7 KB
  unsigned* boffs3 = (unsigned*)(w + 284204928);    // 4.7 KB
  unsigned short* rank3 = (unsigned short*)(w + 284209792);  // 3.84 MB
  int* ssrc3 = (int*)(w + 288049792);               // 7.68 MB

  __bf16* Wp1p = wpk;
  __bf16* Ws1p = wpk + 16384;
  __bf16* Wn1p = wpk + 2 * 16384;
  __bf16* Wp2p = wpk + 3 * 16384;
  __bf16* Ws2p = wpk + 4 * 16384;
  __bf16* Wn2p = wpk + 5 * 16384;

  const dim3 blk(256);
  const int edgeGrid = (NEDGES + 255) / 256;             // 2500
  const int aggGrid = (NNODES * 16 + 255) / 256;         // 6250
  const int degZeroGrid = (3 * NNODES / 4 + 255) / 256;  // 293

  // pack all weights in one dispatch
  packw6_k<<<48, blk, 0, stream>>>(Wp1, Ws1, Wn1, Wp2, Ws2, Wn2, wpk);

  // batched edge bucketing (counting sort by dst) for all 3 graphs
  zero_k<<<degZeroGrid, blk, 0, stream>>>((float4*)deg3, 3L * NNODES / 4);
  hist_rank3_k<<<dim3(edgeGrid, 3), blk, 0, stream>>>(edges, deg3, rank3);
  blocksum3_k<<<dim3(NB, 3), blk, 0, stream>>>(deg3, bsum3);
  scanb3_k<<<dim3(1, 3), dim3(512), 0, stream>>>(bsum3, boffs3, offs3);
  offsets3_k<<<dim3(NB, 3), blk, 0, stream>>>(deg3, boffs3, offs3);
  scat3_k<<<dim3(edgeGrid, 3), blk, 0, stream>>>(edges, offs3, rank3, ssrc3);

  // head: m1 = relu(feat@Wp1^T + bp1) (bf16), plus featb = bf16(feat)
  gemm_k<0, 0, false, true, true, false, true><<<dim3(GRID1, 1), blk, 0, stream>>>(
      feat, 0, nullptr, 0, Wp1p, nullptr, bp1, nullptr, m1, 0, nullptr, featb, NNODES);

  // layer 1 (batched): agg1[g] = segmax_g(m1);
  // h1[g] = agg1[g]@Wn1^T + featb@Ws1^T + b1 (bf16) + fused BN stats
  agg_k<<<dim3(aggGrid, 3), blk, 0, stream>>>((const unsigned short*)m1, 0L,
                                              ssrc3, offs3, (unsigned short*)aggb3);
  gemm_k<1, 1, true, false, true, true, false><<<dim3(GRID1, 3), blk, 0, stream>>>(
      aggb3, SZ_BF, featb, 0, Wn1p, Ws1p, b1, nullptr, h1b3, SZ_BF, pblk3, nullptr, NNODES);
  bn_red1_k<<<dim3(BNRED, 3), blk, 0, stream>>>(pblk3, pblk2_3);
  bn_final2_k<<<dim3(1, 3), blk, 0, stream>>>(pblk2_3, gamma, beta, scsh3);

  // layer 2 (batched): m2[g] = relu(bnrelu(h1[g])@Wp2^T + bp2)
  gemm_k<3, 0, false, true, true, false, false><<<dim3(GRID1, 3), blk, 0, stream>>>(
      h1b3, SZ_BF, nullptr, 0, Wp2p, nullptr, bp2, scsh3, m2_3, SZ_BF, nullptr, nullptr, NNODES);
  agg_k<<<dim3(aggGrid, 3), blk, 0, stream>>>((const unsigned short*)m2_3,
                                              (long)NNODES * FD, ssrc3, offs3,
                                              (unsigned short*)aggb3);
  // out[g] = bnrelu(h1[g])@Ws2^T + agg2[g]@Wn2^T + b2 -> d_out (f32)
  gemm_k<3, 1, true, false, false, false, false><<<dim3(GRID1, 3), blk, 0, stream>>>(
      h1b3, SZ_BF, aggb3, SZ_BF, Ws2p, Wn2p, b2, scsh3, d_out, SZ_F32, nullptr, nullptr, NNODES);
}